// Round 12
// baseline (425.937 us; speedup 1.0000x reference)
//
#include <hip/hip_runtime.h>
#include <hip/hip_bf16.h>
#include <cstdint>
#include <cstddef>

constexpr int C_  = 256;
constexpr int H_  = 224;
constexpr int W_  = 224;
constexpr int P_  = 49;
constexpr int M_  = 1024;
constexpr int HW_ = H_ * W_;

constexpr size_t IMG_ELEMS = (size_t)4 * C_ * H_ * W_;
constexpr size_t SCO_ELEMS = (size_t)4 * M_ * P_ * P_;
constexpr size_t OFF_SC  = IMG_ELEMS;
constexpr size_t OFF_COV = OFF_SC  + SCO_ELEMS;
constexpr size_t OFF_L   = OFF_COV + SCO_ELEMS;
constexpr size_t OFF_EC  = OFF_L   + SCO_ELEMS;

typedef __attribute__((ext_vector_type(8))) short short8;
typedef __attribute__((ext_vector_type(4))) float f32x4;

// Workspace: per-patch bf16 L record = raw copy of the 64x128B swizzled Lb
// LDS region (rows 49..63 zeroed). 4096 * 8192 B = 33.5 MB.
constexpr size_t WSL_PATCH = 8192;
constexpr size_t WS_NEED   = (size_t)4096 * WSL_PATCH;

// K1 LDS map (45,568 B -> 3 blocks/CU):
//   sA  : [0, 32768)        64 rows x 512B bf16, row-XOR-swizzled (49..63 = 0)
//   Gb  : [32768, 39040+1920) 64 rows x 128B bf16 (G-u); Lb overlay; rows
//                            49..63 zeroed in P3 (shipped to ws)
//   Scb : [40960, 47232)... — see offsets below (Gb region is 64 rows now)
constexpr int SA_OFF  = 0;        // 64 rows x 512B = 32768
constexpr int GB_OFF  = 32768;    // 64 x 128B = 8192 (rows 49..63 zeroed)
constexpr int SCB_OFF = 40960;    // 49 x 128B = 6272
constexpr int U_OFF   = 47232;    // 64 f32
constexpr int SMEM_BYTES = 47488;

__device__ __forceinline__ int srowswz(int r) { return ((r ^ (r >> 3)) & 7) << 4; }

__device__ __forceinline__ short f2bf_s(float v) {
    __hip_bfloat16 b = __float2bfloat16(v);
    return *reinterpret_cast<short*>(&b);
}
__device__ __forceinline__ float bf2f_s(short s) {
    __hip_bfloat16 b = *reinterpret_cast<__hip_bfloat16*>(&s);
    return __bfloat162float(b);
}

template<bool SPLIT>
__global__ __launch_bounds__(256, 3)
void psa_kernel(const float* __restrict__ x, const float* __restrict__ betap,
                float* __restrict__ out_img, float* __restrict__ out_sc,
                float* __restrict__ out_cov, float* __restrict__ out_l,
                float* __restrict__ out_ec,
                unsigned char* __restrict__ wsL)
{
    __shared__ __align__(16) unsigned char smem[SMEM_BYTES];
    float* uArr = (float*)(smem + U_OFF);

    const int tid = threadIdx.x;
    const int bid = blockIdx.x;
    const int bm  = ((bid & 7) << 9) | (bid >> 3);   // XCD-bijective swizzle
    const int b   = bm >> 10;
    const int m   = bm & (M_ - 1);
    const int mh  = m >> 5;
    const int mw  = m & 31;
    const float beta = betap[0];
    const size_t xpatch = (((size_t)b * C_ * H_) + (size_t)mh * 7) * W_ + (size_t)mw * 7;

    const int wid = tid >> 6, lane = tid & 63, l15 = lane & 15, lh = lane >> 4;

    // ---- Phase 0: stage x -> sA. lane = token p; wave wid covers channels
    // [64wid, +64). 8 channels per ds_write_b128; lanes 49..63 write zeros. ----
    {
        const int p = lane;
        const int i = p / 7, j = p - 7 * (p / 7);
        const float* xp = x + xpatch + (size_t)i * W_ + j + (size_t)(64 * wid) * HW_;
        const int swzp = srowswz(p);
        unsigned char* sbase = smem + SA_OFF + p * 512 + 128 * wid;
        #pragma unroll
        for (int g = 0; g < 8; ++g) {
            short8 pk;
            if (p < P_) {
                #pragma unroll
                for (int k = 0; k < 8; ++k)
                    pk[k] = f2bf_s(xp[(size_t)(8 * g + k) * HW_]);
            } else {
                pk = short8{0, 0, 0, 0, 0, 0, 0, 0};
            }
            *(short8*)(sbase + ((16 * g) ^ swzp)) = pk;
        }
    }
    __syncthreads();

    // ---- Phase 1: G = A A^T (MFMA, K=256); G stays in registers ----
    f32x4 gacc[4] = {f32x4{0,0,0,0}, f32x4{0,0,0,0}, f32x4{0,0,0,0}, f32x4{0,0,0,0}};
    {
        const int arow = 16 * wid + l15;
        #pragma unroll
        for (int kc = 0; kc < 8; ++kc) {
            const int cb = 64 * kc + 16 * lh;
            const short8 af = *(const short8*)(smem + SA_OFF + arow * 512 + (cb ^ srowswz(arow)));
            #pragma unroll
            for (int t = 0; t < 4; ++t) {
                const int brow = 16 * t + l15;
                const short8 bf = *(const short8*)(smem + SA_OFF + brow * 512 + (cb ^ srowswz(brow)));
                gacc[t] = __builtin_amdgcn_mfma_f32_16x16x32_bf16(af, bf, gacc[t], 0, 0, 0);
            }
        }
    }

    // ---- Phase 2: in-register row stats; u = rowmean (G symmetric) ----
    float mx[4];
    {
        #pragma unroll
        for (int r = 0; r < 4; ++r) {
            const int p = 16 * wid + 4 * lh + r;
            float m_ = fmaxf(fmaxf(gacc[0][r], gacc[1][r]), gacc[2][r]);
            m_ = fmaxf(m_, (l15 == 0) ? gacc[3][r] : -3.4e38f);
            float s_ = gacc[0][r] + gacc[1][r] + gacc[2][r] + ((l15 == 0) ? gacc[3][r] : 0.f);
            #pragma unroll
            for (int d = 1; d < 16; d <<= 1) {
                m_ = fmaxf(m_, __shfl_xor(m_, d));
                s_ += __shfl_xor(s_, d);
            }
            mx[r] = m_;
            if (l15 == 0 && p <= 48) uArr[p] = s_ * (1.f / 49.f);
        }
    }
    __syncthreads();

    // ---- Phase 3: Gb = bf16(G-u); in-reg exp/rowsum/scale; Scb.
    // Also zero Gb/Lb rows 49..63 (shipped to ws; K2 needs exact zeros). ----
    float sc[4][4];
    {
        for (int s = tid; s < 120; s += 256)
            *(short8*)(smem + GB_OFF + 49 * 128 + s * 16) = short8{0,0,0,0,0,0,0,0};
        #pragma unroll
        for (int r = 0; r < 4; ++r) {
            const int p = 16 * wid + 4 * lh + r;
            if (p <= 48) {
                #pragma unroll
                for (int t = 0; t < 4; ++t) {
                    const int qv = 16 * t + l15;
                    const float gv = (qv <= 48) ? (gacc[t][r] - uArr[qv]) : 0.f;
                    *(__hip_bfloat16*)(smem + GB_OFF + p * 128 + ((2 * qv) ^ srowswz(p))) =
                        __float2bfloat16(gv);
                }
            }
            float e[4];
            #pragma unroll
            for (int t = 0; t < 4; ++t) {
                const int qv = 16 * t + l15;
                e[t] = (qv <= 48) ? __expf(gacc[t][r] - mx[r]) : 0.f;
            }
            float s_ = e[0] + e[1] + e[2] + e[3];
            #pragma unroll
            for (int d = 1; d < 16; d <<= 1) s_ += __shfl_xor(s_, d);
            const float rinv = 1.f / s_;
            #pragma unroll
            for (int t = 0; t < 4; ++t) sc[t][r] = e[t] * rinv;
            if (p <= 48) {
                #pragma unroll
                for (int t = 0; t < 4; ++t) {
                    const int qv = 16 * t + l15;
                    *(__hip_bfloat16*)(smem + SCB_OFF + p * 128 + ((2 * qv) ^ srowswz(p))) =
                        __float2bfloat16(sc[t][r]);
                    if (!SPLIT && qv <= 48)
                        out_sc[(size_t)bm * (P_ * P_) + p * 49 + qv] = sc[t][r];
                }
            }
        }
    }
    __syncthreads();

    // ---- Phase 4: cov MFMA: cacc = Gb . Scb^T (K=64); T2 = rowmean in-reg ----
    f32x4 cacc[4] = {f32x4{0,0,0,0}, f32x4{0,0,0,0}, f32x4{0,0,0,0}, f32x4{0,0,0,0}};
    {
        const int arow = 16 * wid + l15;
        #pragma unroll
        for (int kc = 0; kc < 2; ++kc) {
            const int cb = 64 * kc + 16 * lh;
            const short8 af = *(const short8*)(smem + GB_OFF + arow * 128 + (cb ^ srowswz(arow)));
            #pragma unroll
            for (int t = 0; t < 4; ++t) {
                const int brow = 16 * t + l15;
                const short8 bf = *(const short8*)(smem + SCB_OFF + brow * 128 + (cb ^ srowswz(brow)));
                cacc[t] = __builtin_amdgcn_mfma_f32_16x16x32_bf16(af, bf, cacc[t], 0, 0, 0);
            }
        }
    }
    float t2[4];
    {
        #pragma unroll
        for (int r = 0; r < 4; ++r) {
            float s_ = cacc[0][r] + cacc[1][r] + cacc[2][r] + ((l15 == 0) ? cacc[3][r] : 0.f);
            #pragma unroll
            for (int d = 1; d < 16; d <<= 1) s_ += __shfl_xor(s_, d);
            t2[r] = s_ * (1.f / 49.f);
        }
    }
    __syncthreads();

    // ---- Phase 5: cv = (cacc - T2)/49; L = Sc + cv; Lb LDS write ----
    {
        #pragma unroll
        for (int t = 0; t < 4; ++t) {
            const int qv = 16 * t + l15;
            #pragma unroll
            for (int r = 0; r < 4; ++r) {
                const int p = 16 * wid + 4 * lh + r;
                if (p <= 48 && qv <= 48) {
                    const float cv = (cacc[t][r] - t2[r]) * (1.f / 49.f);
                    const float lv = sc[t][r] + cv;
                    if (!SPLIT) {
                        out_cov[(size_t)bm * (P_ * P_) + p * 49 + qv] = cv;
                        out_l  [(size_t)bm * (P_ * P_) + p * 49 + qv] = lv;
                    }
                    *(__hip_bfloat16*)(smem + GB_OFF + p * 128 + ((2 * qv) ^ srowswz(p))) =
                        __float2bfloat16(lv);
                }
            }
        }
    }
    __syncthreads();

    if (SPLIT) {
        // ---- Ship Lb record (8 KB raw swizzled bytes) + deferred fp32 outs ----
        unsigned char* dst = wsL + (size_t)bm * WSL_PATCH;
        for (int s = tid; s < 512; s += 256)
            *(short8*)(dst + s * 16) = *(const short8*)(smem + GB_OFF + s * 16);
        float* sc_g  = out_sc  + (size_t)bm * (P_ * P_);
        float* cov_g = out_cov + (size_t)bm * (P_ * P_);
        float* l_g   = out_l   + (size_t)bm * (P_ * P_);
        for (int e = tid; e < P_ * P_; e += 256) {
            const int p = e / 49, q = e - 49 * p;
            const float scv = bf2f_s(*(const short*)(smem + SCB_OFF + p * 128 + ((2 * q) ^ srowswz(p))));
            const float lvv = bf2f_s(*(const short*)(smem + GB_OFF  + p * 128 + ((2 * q) ^ srowswz(p))));
            sc_g[e]  = scv;
            l_g[e]   = lvv;
            cov_g[e] = lvv - scv;
        }
    } else {
        // ---- Fallback: Ec^T = A^T.L^T + direct scatter (R11 behavior) ----
        f32x4 acc[4][4];
        #pragma unroll
        for (int i = 0; i < 4; ++i)
            #pragma unroll
            for (int j2 = 0; j2 < 4; ++j2) acc[i][j2] = f32x4{0, 0, 0, 0};
        #pragma unroll
        for (int kc = 0; kc < 2; ++kc) {
            const int cb = 64 * kc + 16 * lh;
            short8 bf[4];
            #pragma unroll
            for (int pt = 0; pt < 4; ++pt) {
                const int brow = 16 * pt + l15;
                bf[pt] = *(const short8*)(smem + GB_OFF + brow * 128 + (cb ^ srowswz(brow)));
            }
            #pragma unroll
            for (int ct = 0; ct < 4; ++ct) {
                const int c = 64 * wid + 16 * ct + l15;
                short8 af;
                #pragma unroll
                for (int j = 0; j < 8; ++j) {
                    const int q2 = 32 * kc + 8 * lh + j;
                    af[j] = *(const short*)(smem + SA_OFF + q2 * 512 + ((2 * c) ^ srowswz(q2)));
                }
                #pragma unroll
                for (int pt = 0; pt < 4; ++pt)
                    acc[ct][pt] = __builtin_amdgcn_mfma_f32_16x16x32_bf16(af, bf[pt], acc[ct][pt], 0, 0, 0);
            }
        }
        #pragma unroll
        for (int pt = 0; pt < 4; ++pt) {
            const int p = 16 * pt + l15;
            if (p > 48) continue;
            const int i = p / 7, j = p - 7 * (p / 7);
            const size_t base = xpatch + (size_t)i * W_ + j;
            #pragma unroll
            for (int ct = 0; ct < 4; ++ct) {
                #pragma unroll
                for (int r = 0; r < 4; ++r) {
                    const int c = 64 * wid + 16 * ct + 4 * lh + r;
                    const size_t g = base + (size_t)c * HW_;
                    const float ec = acc[ct][pt][r];
                    const float xv = bf2f_s(*(const short*)(smem + SA_OFF + p * 512 + ((2 * c) ^ srowswz(p))));
                    out_ec [g] = ec;
                    out_img[g] = xv * fmaf(beta, ec, xv);
                }
            }
        }
    }
}

// K2: block = (b, mh, 8-patch group). Wave's 2 patches' L^T fragments live in
// 64 VGPRs (loaded once from wsL). Loop 8 chunks of 32 channels: stage x
// strip -> LDS (bf16, swizzled), MFMA Ec^T = A^T.L^T, store out_ec/out_img.
// All 8 patches' 28B segments of each 64B output line written by THIS block
// within one chunk -> L2 merges to full lines.
__global__ __launch_bounds__(256, 2)
void ec_kernel(const float* __restrict__ x, const float* __restrict__ betap,
               const unsigned char* __restrict__ wsL,
               float* __restrict__ out_img, float* __restrict__ out_ec)
{
    __shared__ __align__(16) unsigned char xs[8 * 4096];   // [patch][32cl][64q] bf16

    const int bid   = blockIdx.x;
    const int group = bid >> 7;          // high bits: 4 groups of a strip share XCD
    const int strip = bid & 127;         // b*32 + mh
    const int b  = strip >> 5, mh = strip & 31;
    const int mw0 = group << 3;
    const int tid = threadIdx.x;
    const int wid = tid >> 6, lane = tid & 63, l15 = lane & 15, lh = lane >> 4;
    const float beta = betap[0];

    // Zero whole staging buffer once (q-slots 49..63 stay 0 forever).
    for (int s = tid; s < 2048; s += 256)
        *(short8*)(xs + s * 16) = short8{0, 0, 0, 0, 0, 0, 0, 0};

    // Load this wave's 2 patches' L^T fragments into registers.
    short8 bfrag[2][4][2];
    #pragma unroll
    for (int pp = 0; pp < 2; ++pp) {
        const int patch = 2 * wid + pp;
        const int bm = (b << 10) + (mh << 5) + (mw0 + patch);
        const unsigned char* Lbase = wsL + (size_t)bm * WSL_PATCH;
        #pragma unroll
        for (int pt = 0; pt < 4; ++pt) {
            const int row = 16 * pt + l15;
            #pragma unroll
            for (int kc = 0; kc < 2; ++kc)
                bfrag[pp][pt][kc] = *(const short8*)(Lbase + row * 128 +
                                     ((64 * kc + 16 * lh) ^ srowswz(row)));
        }
    }
    __syncthreads();   // zero-fill complete before staging

    for (int ch = 0; ch < 8; ++ch) {
        const int c0 = ch * 32;
        // Stage: 32c x 7i rows of 56 floats (full-line reads), transposed to
        // [patch][cl][q] bf16 with bank-spreading XOR.
        for (int s = tid; s < 3136; s += 256) {
            const int cl  = s / 98;
            const int rem = s - cl * 98;
            const int i   = rem / 14;
            const int w4  = rem - i * 14;
            const float4 v = *(const float4*)(x +
                ((size_t)(b * C_ + c0 + cl) * H_ + (size_t)(mh * 7 + i)) * W_ +
                mw0 * 7 + w4 * 4);
            #pragma unroll
            for (int e = 0; e < 4; ++e) {
                const int w = w4 * 4 + e;
                const int patch = w / 7, j = w - 7 * patch;
                const int q = 7 * i + j;
                *(short*)(xs + patch * 4096 + cl * 128 +
                          ((2 * q) ^ srowswz(cl) ^ (patch << 4))) =
                    f2bf_s(((const float*)&v)[e]);
            }
        }
        __syncthreads();

        #pragma unroll
        for (int pp = 0; pp < 2; ++pp) {
            const int patch = 2 * wid + pp;
            f32x4 acc[2][4];
            #pragma unroll
            for (int ct = 0; ct < 2; ++ct)
                #pragma unroll
                for (int pt = 0; pt < 4; ++pt) acc[ct][pt] = f32x4{0, 0, 0, 0};
            #pragma unroll
            for (int kc = 0; kc < 2; ++kc) {
                #pragma unroll
                for (int ct = 0; ct < 2; ++ct) {
                    const int cl = 16 * ct + l15;
                    const short8 af = *(const short8*)(xs + patch * 4096 + cl * 128 +
                        ((64 * kc + 16 * lh) ^ srowswz(cl) ^ (patch << 4)));
                    #pragma unroll
                    for (int pt = 0; pt < 4; ++pt)
                        acc[ct][pt] = __builtin_amdgcn_mfma_f32_16x16x32_bf16(
                            af, bfrag[pp][pt][kc], acc[ct][pt], 0, 0, 0);
                }
            }
            // Stores: lane l15 = token p (28B segments), siblings complete lines.
            #pragma unroll
            for (int pt = 0; pt < 4; ++pt) {
                const int p = 16 * pt + l15;
                if (p > 48) continue;
                const int i = p / 7, j = p - 7 * (p / 7);
                #pragma unroll
                for (int ct = 0; ct < 2; ++ct) {
                    #pragma unroll
                    for (int r = 0; r < 4; ++r) {
                        const int cl = 16 * ct + 4 * lh + r;
                        const int c  = c0 + cl;
                        const size_t g = ((size_t)(b * C_ + c) * H_ +
                                          (size_t)(mh * 7 + i)) * W_ +
                                          (mw0 + patch) * 7 + j;
                        const float ec = acc[ct][pt][r];
                        const float xv = bf2f_s(*(const short*)(xs + patch * 4096 +
                            cl * 128 + ((2 * p) ^ srowswz(cl) ^ (patch << 4))));
                        out_ec [g] = ec;
                        out_img[g] = xv * fmaf(beta, ec, xv);
                    }
                }
            }
        }
        __syncthreads();
    }
}

extern "C" void kernel_launch(void* const* d_in, const int* in_sizes, int n_in,
                              void* d_out, int out_size, void* d_ws, size_t ws_size,
                              hipStream_t stream) {
    const float* x    = (const float*)d_in[0];
    const float* beta = (const float*)d_in[1];
    float* out = (float*)d_out;

    if (ws_size >= WS_NEED) {
        unsigned char* wsL = (unsigned char*)d_ws;
        psa_kernel<true><<<dim3(4 * M_), dim3(256), 0, stream>>>(
            x, beta, out, out + OFF_SC, out + OFF_COV, out + OFF_L, out + OFF_EC,
            wsL);
        ec_kernel<<<dim3(512), dim3(256), 0, stream>>>(
            x, beta, wsL, out, out + OFF_EC);
    } else {
        psa_kernel<false><<<dim3(4 * M_), dim3(256), 0, stream>>>(
            x, beta, out, out + OFF_SC, out + OFF_COV, out + OFF_L, out + OFF_EC,
            nullptr);
    }
}

// Round 13
// 306.341 us; speedup vs baseline: 1.3904x; 1.3904x over previous
//
#include <hip/hip_runtime.h>
#include <hip/hip_bf16.h>
#include <cstdint>
#include <cstddef>

constexpr int C_  = 256;
constexpr int H_  = 224;
constexpr int W_  = 224;
constexpr int P_  = 49;
constexpr int M_  = 1024;
constexpr int HW_ = H_ * W_;

constexpr size_t IMG_ELEMS = (size_t)4 * C_ * H_ * W_;
constexpr size_t SCO_ELEMS = (size_t)4 * M_ * P_ * P_;
constexpr size_t OFF_SC  = IMG_ELEMS;
constexpr size_t OFF_COV = OFF_SC  + SCO_ELEMS;
constexpr size_t OFF_L   = OFF_COV + SCO_ELEMS;
constexpr size_t OFF_EC  = OFF_L   + SCO_ELEMS;

typedef __attribute__((ext_vector_type(8))) short short8;
typedef __attribute__((ext_vector_type(4))) float f32x4;

// Workspace: per-patch DENSE bf16 L record, row-major [64 p][64 q] (rows/cols
// 49..63 zero). 4096 * 8192 B = 33.5 MB (L3-resident for K2's re-reads).
constexpr size_t WSL_PATCH = 8192;
constexpr size_t WS_NEED   = (size_t)4096 * WSL_PATCH;

// K1 LDS map (47,488 B -> 3 blocks/CU):
constexpr int SA_OFF  = 0;        // 64 rows x 512B bf16 swizzled (49..63 = 0)
constexpr int GB_OFF  = 32768;    // 64 x 128B bf16 (G-u) -> Lb overlay
constexpr int SCB_OFF = 40960;    // 49 x 128B bf16 Sc
constexpr int U_OFF   = 47232;    // 64 f32
constexpr int SMEM_BYTES = 47488;

__device__ __forceinline__ int srowswz(int r) { return ((r ^ (r >> 3)) & 7) << 4; }

__device__ __forceinline__ short f2bf_s(float v) {
    __hip_bfloat16 b = __float2bfloat16(v);
    return *reinterpret_cast<short*>(&b);
}
__device__ __forceinline__ float bf2f_s(short s) {
    __hip_bfloat16 b = *reinterpret_cast<__hip_bfloat16*>(&s);
    return __bfloat162float(b);
}

template<bool SPLIT>
__global__ __launch_bounds__(256, 3)
void psa_kernel(const float* __restrict__ x, const float* __restrict__ betap,
                float* __restrict__ out_img, float* __restrict__ out_sc,
                float* __restrict__ out_cov, float* __restrict__ out_l,
                float* __restrict__ out_ec,
                unsigned char* __restrict__ wsL)
{
    __shared__ __align__(16) unsigned char smem[SMEM_BYTES];
    float* uArr = (float*)(smem + U_OFF);

    const int tid = threadIdx.x;
    const int bid = blockIdx.x;
    const int bm  = ((bid & 7) << 9) | (bid >> 3);   // XCD-bijective swizzle
    const int b   = bm >> 10;
    const int m   = bm & (M_ - 1);
    const int mh  = m >> 5;
    const int mw  = m & 31;
    const float beta = betap[0];
    const size_t xpatch = (((size_t)b * C_ * H_) + (size_t)mh * 7) * W_ + (size_t)mw * 7;

    const int wid = tid >> 6, lane = tid & 63, l15 = lane & 15, lh = lane >> 4;

    // ---- Phase 0: stage x -> sA (lane = token, 8ch per ds_write_b128) ----
    {
        const int p = lane;
        const int i = p / 7, j = p - 7 * (p / 7);
        const float* xp = x + xpatch + (size_t)i * W_ + j + (size_t)(64 * wid) * HW_;
        const int swzp = srowswz(p);
        unsigned char* sbase = smem + SA_OFF + p * 512 + 128 * wid;
        #pragma unroll
        for (int g = 0; g < 8; ++g) {
            short8 pk;
            if (p < P_) {
                #pragma unroll
                for (int k = 0; k < 8; ++k)
                    pk[k] = f2bf_s(xp[(size_t)(8 * g + k) * HW_]);
            } else {
                pk = short8{0, 0, 0, 0, 0, 0, 0, 0};
            }
            *(short8*)(sbase + ((16 * g) ^ swzp)) = pk;
        }
    }
    __syncthreads();

    // ---- Phase 1: G = A A^T (MFMA, K=256); G stays in registers ----
    f32x4 gacc[4] = {f32x4{0,0,0,0}, f32x4{0,0,0,0}, f32x4{0,0,0,0}, f32x4{0,0,0,0}};
    {
        const int arow = 16 * wid + l15;
        #pragma unroll
        for (int kc = 0; kc < 8; ++kc) {
            const int cb = 64 * kc + 16 * lh;
            const short8 af = *(const short8*)(smem + SA_OFF + arow * 512 + (cb ^ srowswz(arow)));
            #pragma unroll
            for (int t = 0; t < 4; ++t) {
                const int brow = 16 * t + l15;
                const short8 bf = *(const short8*)(smem + SA_OFF + brow * 512 + (cb ^ srowswz(brow)));
                gacc[t] = __builtin_amdgcn_mfma_f32_16x16x32_bf16(af, bf, gacc[t], 0, 0, 0);
            }
        }
    }

    // ---- Phase 2: in-register row stats; u = rowmean (G symmetric) ----
    float mx[4];
    {
        #pragma unroll
        for (int r = 0; r < 4; ++r) {
            const int p = 16 * wid + 4 * lh + r;
            float m_ = fmaxf(fmaxf(gacc[0][r], gacc[1][r]), gacc[2][r]);
            m_ = fmaxf(m_, (l15 == 0) ? gacc[3][r] : -3.4e38f);
            float s_ = gacc[0][r] + gacc[1][r] + gacc[2][r] + ((l15 == 0) ? gacc[3][r] : 0.f);
            #pragma unroll
            for (int d = 1; d < 16; d <<= 1) {
                m_ = fmaxf(m_, __shfl_xor(m_, d));
                s_ += __shfl_xor(s_, d);
            }
            mx[r] = m_;
            if (l15 == 0 && p <= 48) uArr[p] = s_ * (1.f / 49.f);
        }
    }
    __syncthreads();

    // ---- Phase 3: Gb = bf16(G-u); in-reg exp/rowsum/scale; Scb ----
    float sc[4][4];
    {
        #pragma unroll
        for (int r = 0; r < 4; ++r) {
            const int p = 16 * wid + 4 * lh + r;
            if (p <= 48) {
                #pragma unroll
                for (int t = 0; t < 4; ++t) {
                    const int qv = 16 * t + l15;
                    const float gv = (qv <= 48) ? (gacc[t][r] - uArr[qv]) : 0.f;
                    *(__hip_bfloat16*)(smem + GB_OFF + p * 128 + ((2 * qv) ^ srowswz(p))) =
                        __float2bfloat16(gv);
                }
            }
            float e[4];
            #pragma unroll
            for (int t = 0; t < 4; ++t) {
                const int qv = 16 * t + l15;
                e[t] = (qv <= 48) ? __expf(gacc[t][r] - mx[r]) : 0.f;
            }
            float s_ = e[0] + e[1] + e[2] + e[3];
            #pragma unroll
            for (int d = 1; d < 16; d <<= 1) s_ += __shfl_xor(s_, d);
            const float rinv = 1.f / s_;
            #pragma unroll
            for (int t = 0; t < 4; ++t) sc[t][r] = e[t] * rinv;
            if (p <= 48) {
                #pragma unroll
                for (int t = 0; t < 4; ++t) {
                    const int qv = 16 * t + l15;
                    *(__hip_bfloat16*)(smem + SCB_OFF + p * 128 + ((2 * qv) ^ srowswz(p))) =
                        __float2bfloat16(sc[t][r]);
                    if (!SPLIT && qv <= 48)
                        out_sc[(size_t)bm * (P_ * P_) + p * 49 + qv] = sc[t][r];
                }
            }
        }
    }
    __syncthreads();

    // ---- Phase 4: cov MFMA: cacc = Gb . Scb^T (K=64); T2 = rowmean in-reg ----
    f32x4 cacc[4] = {f32x4{0,0,0,0}, f32x4{0,0,0,0}, f32x4{0,0,0,0}, f32x4{0,0,0,0}};
    {
        const int arow = 16 * wid + l15;
        #pragma unroll
        for (int kc = 0; kc < 2; ++kc) {
            const int cb = 64 * kc + 16 * lh;
            const short8 af = *(const short8*)(smem + GB_OFF + arow * 128 + (cb ^ srowswz(arow)));
            #pragma unroll
            for (int t = 0; t < 4; ++t) {
                const int brow = 16 * t + l15;
                const short8 bf = *(const short8*)(smem + SCB_OFF + brow * 128 + (cb ^ srowswz(brow)));
                cacc[t] = __builtin_amdgcn_mfma_f32_16x16x32_bf16(af, bf, cacc[t], 0, 0, 0);
            }
        }
    }
    float t2[4];
    {
        #pragma unroll
        for (int r = 0; r < 4; ++r) {
            float s_ = cacc[0][r] + cacc[1][r] + cacc[2][r] + ((l15 == 0) ? cacc[3][r] : 0.f);
            #pragma unroll
            for (int d = 1; d < 16; d <<= 1) s_ += __shfl_xor(s_, d);
            t2[r] = s_ * (1.f / 49.f);
        }
    }
    __syncthreads();

    // ---- Phase 5: cv = (cacc - T2)/49; L = Sc + cv; Lb LDS write ----
    {
        #pragma unroll
        for (int t = 0; t < 4; ++t) {
            const int qv = 16 * t + l15;
            #pragma unroll
            for (int r = 0; r < 4; ++r) {
                const int p = 16 * wid + 4 * lh + r;
                if (p <= 48 && qv <= 48) {
                    const float cv = (cacc[t][r] - t2[r]) * (1.f / 49.f);
                    const float lv = sc[t][r] + cv;
                    if (!SPLIT) {
                        out_cov[(size_t)bm * (P_ * P_) + p * 49 + qv] = cv;
                        out_l  [(size_t)bm * (P_ * P_) + p * 49 + qv] = lv;
                    }
                    *(__hip_bfloat16*)(smem + GB_OFF + p * 128 + ((2 * qv) ^ srowswz(p))) =
                        __float2bfloat16(lv);
                }
            }
        }
    }
    __syncthreads();

    if (SPLIT) {
        // ---- Ship DENSE L [64 p][64 q] bf16 (rows>=49 zero; cols 49..63
        // already zero in Lb). Thread t: row p=t>>2, q-seg (t&3)*16. ----
        unsigned char* dst = wsL + (size_t)bm * WSL_PATCH;
        {
            const int p  = tid >> 2;
            const int qs = (tid & 3) << 4;
            short8 v0 = short8{0,0,0,0,0,0,0,0}, v1 = v0;
            if (p < P_) {
                #pragma unroll
                for (int k = 0; k < 8; ++k) {
                    v0[k] = *(const short*)(smem + GB_OFF + p * 128 + ((2 * (qs + k))     ^ srowswz(p)));
                    v1[k] = *(const short*)(smem + GB_OFF + p * 128 + ((2 * (qs + 8 + k)) ^ srowswz(p)));
                }
            }
            *(short8*)(dst + p * 128 + qs * 2)      = v0;
            *(short8*)(dst + p * 128 + qs * 2 + 16) = v1;
        }
        // Deferred fp32 Sc/cov/L outputs (bf16-rounded; rel err ~0.4%).
        float* sc_g  = out_sc  + (size_t)bm * (P_ * P_);
        float* cov_g = out_cov + (size_t)bm * (P_ * P_);
        float* l_g   = out_l   + (size_t)bm * (P_ * P_);
        for (int e = tid; e < P_ * P_; e += 256) {
            const int p = e / 49, q = e - 49 * p;
            const float scv = bf2f_s(*(const short*)(smem + SCB_OFF + p * 128 + ((2 * q) ^ srowswz(p))));
            const float lvv = bf2f_s(*(const short*)(smem + GB_OFF  + p * 128 + ((2 * q) ^ srowswz(p))));
            sc_g[e]  = scv;
            l_g[e]   = lvv;
            cov_g[e] = lvv - scv;
        }
    } else {
        // ---- Fallback: Ec^T = A^T.L^T + direct scatter (R11 behavior) ----
        f32x4 acc[4][4];
        #pragma unroll
        for (int i = 0; i < 4; ++i)
            #pragma unroll
            for (int j2 = 0; j2 < 4; ++j2) acc[i][j2] = f32x4{0, 0, 0, 0};
        #pragma unroll
        for (int kc = 0; kc < 2; ++kc) {
            const int cb = 64 * kc + 16 * lh;
            short8 bf[4];
            #pragma unroll
            for (int pt = 0; pt < 4; ++pt) {
                const int brow = 16 * pt + l15;
                bf[pt] = *(const short8*)(smem + GB_OFF + brow * 128 + (cb ^ srowswz(brow)));
            }
            #pragma unroll
            for (int ct = 0; ct < 4; ++ct) {
                const int c = 64 * wid + 16 * ct + l15;
                short8 af;
                #pragma unroll
                for (int j = 0; j < 8; ++j) {
                    const int q2 = 32 * kc + 8 * lh + j;
                    af[j] = *(const short*)(smem + SA_OFF + q2 * 512 + ((2 * c) ^ srowswz(q2)));
                }
                #pragma unroll
                for (int pt = 0; pt < 4; ++pt)
                    acc[ct][pt] = __builtin_amdgcn_mfma_f32_16x16x32_bf16(af, bf[pt], acc[ct][pt], 0, 0, 0);
            }
        }
        #pragma unroll
        for (int pt = 0; pt < 4; ++pt) {
            const int p = 16 * pt + l15;
            if (p > 48) continue;
            const int i = p / 7, j = p - 7 * (p / 7);
            const size_t base = xpatch + (size_t)i * W_ + j;
            #pragma unroll
            for (int ct = 0; ct < 4; ++ct) {
                #pragma unroll
                for (int r = 0; r < 4; ++r) {
                    const int c = 64 * wid + 16 * ct + 4 * lh + r;
                    const size_t g = base + (size_t)c * HW_;
                    const float ec = acc[ct][pt][r];
                    const float xv = bf2f_s(*(const short*)(smem + SA_OFF + p * 512 + ((2 * c) ^ srowswz(p))));
                    out_ec [g] = ec;
                    out_img[g] = xv * fmaf(beta, ec, xv);
                }
            }
        }
    }
}

// K2: block = (b, mh, half-strip hg of 16 patches, 16-channel chunk cg).
// Grid 4096. Stage x [16c][7i][112w] bf16 (coalesced float4 in, b64 LDS
// writes); each wave MFMAs 4 patches sequentially (B = dense L from wsL,
// b128 global loads; A = 16 scalar LDS reads/patch); transpose via Ec LDS;
// emit out_img/out_ec as full-line contiguous float4 stores (16 patches x
// 28B = 448B = 7 exact lines -> zero partial-line amplification).
constexpr int K2_RS = 232;                 // LDS row stride bytes (116 bf16)
constexpr int K2_CS = 7 * K2_RS;           // channel stride = 1624 B
constexpr int K2_XS = 0;                   // x buffer
constexpr int K2_EC = 16 * K2_CS;          // Ec buffer @ 25,984
constexpr int K2_SMEM = 2 * 16 * K2_CS;    // 51,968 B -> 3 blocks/CU

__global__ __launch_bounds__(256, 3)
void ec2_kernel(const float* __restrict__ x, const float* __restrict__ betap,
                const unsigned char* __restrict__ wsL,
                float* __restrict__ out_img, float* __restrict__ out_ec)
{
    __shared__ __align__(16) unsigned char smem[K2_SMEM];

    const int bid = blockIdx.x;
    const int cg  = bid & 15;
    const int hg  = (bid >> 4) & 1;
    const int mh  = (bid >> 5) & 31;
    const int b   = bid >> 10;
    const int c0  = cg * 16;
    const int tid = threadIdx.x;
    const int wid = tid >> 6, lane = tid & 63, l15 = lane & 15, lh = lane >> 4;
    const float beta = betap[0];

    // Base of (c0, mh*7, hg*112) in the image.
    const size_t gbase = ((size_t)(b * C_ + c0) * H_ + (size_t)mh * 7) * W_ + hg * 112;

    // ---- Stage x: 16c x 7i x 28 float4 (full-line reads) -> bf16 LDS ----
    for (int s = tid; s < 3136; s += 256) {
        const int c   = s / 196;
        const int rem = s - c * 196;
        const int i   = rem / 28;
        const int w4  = rem - i * 28;
        const float4 v = *(const float4*)(x + gbase + (size_t)c * HW_ + (size_t)i * W_ + w4 * 4);
        short vv[4];
        #pragma unroll
        for (int e = 0; e < 4; ++e) vv[e] = f2bf_s(((const float*)&v)[e]);
        *(uint2*)(smem + K2_XS + c * K2_CS + i * K2_RS + w4 * 8) = *(const uint2*)vv;
    }
    __syncthreads();

    // ---- MFMA: wave wid owns patches 4*wid .. 4*wid+3 (local), sequential ----
    for (int pp = 0; pp < 4; ++pp) {
        const int pl = 4 * wid + pp;                   // local patch 0..15
        const int bm = (b << 10) + (mh << 5) + hg * 16 + pl;
        const unsigned char* Lb = wsL + (size_t)bm * WSL_PATCH;

        short8 bf[4][2];
        #pragma unroll
        for (int pt = 0; pt < 4; ++pt)
            #pragma unroll
            for (int kc = 0; kc < 2; ++kc)
                bf[pt][kc] = *(const short8*)(Lb + (16 * pt + l15) * 128 + kc * 64 + 16 * lh);

        f32x4 acc[4] = {f32x4{0,0,0,0}, f32x4{0,0,0,0}, f32x4{0,0,0,0}, f32x4{0,0,0,0}};
        #pragma unroll
        for (int kc = 0; kc < 2; ++kc) {
            short8 af;
            #pragma unroll
            for (int j = 0; j < 8; ++j) {
                const int q  = 32 * kc + 8 * lh + j;
                const int qc = (q <= 48) ? q : 0;      // L rows q>=49 are zero
                const int iq = qc / 7, jq = qc - 7 * iq;
                af[j] = *(const short*)(smem + K2_XS + l15 * K2_CS + iq * K2_RS + (pl * 7 + jq) * 2);
            }
            #pragma unroll
            for (int pt = 0; pt < 4; ++pt)
                acc[pt] = __builtin_amdgcn_mfma_f32_16x16x32_bf16(af, bf[pt][kc], acc[pt], 0, 0, 0);
        }

        // Transpose-stage Ec to LDS: lane col p=16pt+l15, rows c=4lh+r.
        #pragma unroll
        for (int pt = 0; pt < 4; ++pt) {
            const int p = 16 * pt + l15;
            if (p > 48) continue;
            const int i = p / 7, j = p - 7 * (p / 7);
            const int w = pl * 7 + j;
            #pragma unroll
            for (int r = 0; r < 4; ++r) {
                const int c = 4 * lh + r;
                *(short*)(smem + K2_EC + c * K2_CS + i * K2_RS + w * 2) = f2bf_s(acc[pt][r]);
            }
        }
    }
    __syncthreads();

    // ---- Emit: full-line float4 stores ----
    for (int s = tid; s < 3136; s += 256) {
        const int c   = s / 196;
        const int rem = s - c * 196;
        const int i   = rem / 28;
        const int w4  = rem - i * 28;
        const uint2 epk = *(const uint2*)(smem + K2_EC + c * K2_CS + i * K2_RS + w4 * 8);
        const uint2 xpk = *(const uint2*)(smem + K2_XS + c * K2_CS + i * K2_RS + w4 * 8);
        const short* ep = (const short*)&epk;
        const short* xp = (const short*)&xpk;
        float4 ve, vo;
        #pragma unroll
        for (int e = 0; e < 4; ++e) {
            const float ec = bf2f_s(ep[e]);
            const float xv = bf2f_s(xp[e]);
            ((float*)&ve)[e] = ec;
            ((float*)&vo)[e] = xv * fmaf(beta, ec, xv);
        }
        const size_t g = gbase + (size_t)c * HW_ + (size_t)i * W_ + w4 * 4;
        *(float4*)&out_ec [g] = ve;
        *(float4*)&out_img[g] = vo;
    }
}

extern "C" void kernel_launch(void* const* d_in, const int* in_sizes, int n_in,
                              void* d_out, int out_size, void* d_ws, size_t ws_size,
                              hipStream_t stream) {
    const float* x    = (const float*)d_in[0];
    const float* beta = (const float*)d_in[1];
    float* out = (float*)d_out;

    if (ws_size >= WS_NEED) {
        unsigned char* wsL = (unsigned char*)d_ws;
        psa_kernel<true><<<dim3(4 * M_), dim3(256), 0, stream>>>(
            x, beta, out, out + OFF_SC, out + OFF_COV, out + OFF_L, out + OFF_EC,
            wsL);
        ec2_kernel<<<dim3(4096), dim3(256), 0, stream>>>(
            x, beta, wsL, out, out + OFF_EC);
    } else {
        psa_kernel<false><<<dim3(4 * M_), dim3(256), 0, stream>>>(
            x, beta, out, out + OFF_SC, out + OFF_COV, out + OFF_L, out + OFF_EC,
            nullptr);
    }
}

// Round 14
// 279.200 us; speedup vs baseline: 1.5256x; 1.0972x over previous
//
#include <hip/hip_runtime.h>
#include <hip/hip_bf16.h>
#include <cstdint>
#include <cstddef>

constexpr int C_  = 256;
constexpr int H_  = 224;
constexpr int W_  = 224;
constexpr int P_  = 49;
constexpr int M_  = 1024;
constexpr int HW_ = H_ * W_;

constexpr size_t IMG_ELEMS = (size_t)4 * C_ * H_ * W_;
constexpr size_t SCO_ELEMS = (size_t)4 * M_ * P_ * P_;
constexpr size_t OFF_SC  = IMG_ELEMS;
constexpr size_t OFF_COV = OFF_SC  + SCO_ELEMS;
constexpr size_t OFF_L   = OFF_COV + SCO_ELEMS;
constexpr size_t OFF_EC  = OFF_L   + SCO_ELEMS;

typedef __attribute__((ext_vector_type(8))) short short8;
typedef __attribute__((ext_vector_type(4))) float f32x4;

// Workspace: Ec in WAVE-NATIVE packed layout. Per patch: 4 waves x 2048
// uints; uint = (bf16 Ec[c0+1]<<16)|bf16 Ec[c0] for channel pair.
// Flat index: ((bm*4 + wid)*2048) + ((ct*4 + pt)*2 + rp)*64 + lane.
// Element (c,p): wid=c>>6, ct=(c>>4)&3, lh=(c>>2)&3, r=c&3 (rp=r>>1,
// lo/hi=r&1), pt=p>>4, l15=p&15, lane=lh*16+l15.
// Every psa store instr = 64 lanes x 4B = 256B contiguous (full lines).
constexpr size_t WSP_UINTS = 8192;                       // per patch
constexpr size_t WS_NEED   = (size_t)4096 * WSP_UINTS * 4;   // 134,217,728 B

// K1 LDS map (45,568 B -> 3 blocks/CU):
constexpr int SA_OFF  = 0;        // 64 rows x 512B bf16 swizzled (49..63 = 0)
constexpr int GB_OFF  = 32768;    // 64 x 128B bf16 (G-u) -> Lb overlay (49..63 zeroed)
constexpr int SCB_OFF = 40960;    // 49 x 128B bf16 Sc
constexpr int U_OFF   = 47232;    // 64 f32
constexpr int SMEM_BYTES = 47488;

__device__ __forceinline__ int srowswz(int r) { return ((r ^ (r >> 3)) & 7) << 4; }

__device__ __forceinline__ short f2bf_s(float v) {
    __hip_bfloat16 b = __float2bfloat16(v);
    return *reinterpret_cast<short*>(&b);
}
__device__ __forceinline__ float bf2f_s(short s) {
    __hip_bfloat16 b = *reinterpret_cast<__hip_bfloat16*>(&s);
    return __bfloat162float(b);
}
__device__ __forceinline__ unsigned int packbf(float lo, float hi) {
    return (unsigned int)(unsigned short)f2bf_s(lo) |
           ((unsigned int)(unsigned short)f2bf_s(hi) << 16);
}

template<bool SPLIT>
__global__ __launch_bounds__(256, 3)
void psa_kernel(const float* __restrict__ x, const float* __restrict__ betap,
                float* __restrict__ out_img, float* __restrict__ out_sc,
                float* __restrict__ out_cov, float* __restrict__ out_l,
                float* __restrict__ out_ec,
                unsigned int* __restrict__ ws_ec)
{
    __shared__ __align__(16) unsigned char smem[SMEM_BYTES];
    float* uArr = (float*)(smem + U_OFF);

    const int tid = threadIdx.x;
    const int bid = blockIdx.x;
    const int bm  = ((bid & 7) << 9) | (bid >> 3);   // XCD-bijective swizzle
    const int b   = bm >> 10;
    const int m   = bm & (M_ - 1);
    const int mh  = m >> 5;
    const int mw  = m & 31;
    const float beta = betap[0];
    const size_t xpatch = (((size_t)b * C_ * H_) + (size_t)mh * 7) * W_ + (size_t)mw * 7;

    const int wid = tid >> 6, lane = tid & 63, l15 = lane & 15, lh = lane >> 4;

    // ---- Phase 0: stage x -> sA (lane = token, 8ch per ds_write_b128) ----
    {
        const int p = lane;
        const int i = p / 7, j = p - 7 * (p / 7);
        const float* xp = x + xpatch + (size_t)i * W_ + j + (size_t)(64 * wid) * HW_;
        const int swzp = srowswz(p);
        unsigned char* sbase = smem + SA_OFF + p * 512 + 128 * wid;
        #pragma unroll
        for (int g = 0; g < 8; ++g) {
            short8 pk;
            if (p < P_) {
                #pragma unroll
                for (int k = 0; k < 8; ++k)
                    pk[k] = f2bf_s(xp[(size_t)(8 * g + k) * HW_]);
            } else {
                pk = short8{0, 0, 0, 0, 0, 0, 0, 0};
            }
            *(short8*)(sbase + ((16 * g) ^ swzp)) = pk;
        }
    }
    __syncthreads();

    // ---- Phase 1: G = A A^T (MFMA, K=256); G stays in registers ----
    f32x4 gacc[4] = {f32x4{0,0,0,0}, f32x4{0,0,0,0}, f32x4{0,0,0,0}, f32x4{0,0,0,0}};
    {
        const int arow = 16 * wid + l15;
        #pragma unroll
        for (int kc = 0; kc < 8; ++kc) {
            const int cb = 64 * kc + 16 * lh;
            const short8 af = *(const short8*)(smem + SA_OFF + arow * 512 + (cb ^ srowswz(arow)));
            #pragma unroll
            for (int t = 0; t < 4; ++t) {
                const int brow = 16 * t + l15;
                const short8 bf = *(const short8*)(smem + SA_OFF + brow * 512 + (cb ^ srowswz(brow)));
                gacc[t] = __builtin_amdgcn_mfma_f32_16x16x32_bf16(af, bf, gacc[t], 0, 0, 0);
            }
        }
    }

    // ---- Phase 2: in-register row stats; u = rowmean (G symmetric) ----
    float mx[4];
    {
        #pragma unroll
        for (int r = 0; r < 4; ++r) {
            const int p = 16 * wid + 4 * lh + r;
            float m_ = fmaxf(fmaxf(gacc[0][r], gacc[1][r]), gacc[2][r]);
            m_ = fmaxf(m_, (l15 == 0) ? gacc[3][r] : -3.4e38f);
            float s_ = gacc[0][r] + gacc[1][r] + gacc[2][r] + ((l15 == 0) ? gacc[3][r] : 0.f);
            #pragma unroll
            for (int d = 1; d < 16; d <<= 1) {
                m_ = fmaxf(m_, __shfl_xor(m_, d));
                s_ += __shfl_xor(s_, d);
            }
            mx[r] = m_;
            if (l15 == 0 && p <= 48) uArr[p] = s_ * (1.f / 49.f);
        }
    }
    __syncthreads();

    // ---- Phase 3: Gb = bf16(G-u); in-reg exp/rowsum/scale; Scb.
    // Also zero Gb rows 49..63 (read by phase 6's B-fragments). ----
    float sc[4][4];
    {
        for (int s = tid; s < 120; s += 256)
            *(short8*)(smem + GB_OFF + 49 * 128 + s * 16) = short8{0,0,0,0,0,0,0,0};
        #pragma unroll
        for (int r = 0; r < 4; ++r) {
            const int p = 16 * wid + 4 * lh + r;
            if (p <= 48) {
                #pragma unroll
                for (int t = 0; t < 4; ++t) {
                    const int qv = 16 * t + l15;
                    const float gv = (qv <= 48) ? (gacc[t][r] - uArr[qv]) : 0.f;
                    *(__hip_bfloat16*)(smem + GB_OFF + p * 128 + ((2 * qv) ^ srowswz(p))) =
                        __float2bfloat16(gv);
                }
            }
            float e[4];
            #pragma unroll
            for (int t = 0; t < 4; ++t) {
                const int qv = 16 * t + l15;
                e[t] = (qv <= 48) ? __expf(gacc[t][r] - mx[r]) : 0.f;
            }
            float s_ = e[0] + e[1] + e[2] + e[3];
            #pragma unroll
            for (int d = 1; d < 16; d <<= 1) s_ += __shfl_xor(s_, d);
            const float rinv = 1.f / s_;
            #pragma unroll
            for (int t = 0; t < 4; ++t) sc[t][r] = e[t] * rinv;
            if (p <= 48) {
                #pragma unroll
                for (int t = 0; t < 4; ++t) {
                    const int qv = 16 * t + l15;
                    *(__hip_bfloat16*)(smem + SCB_OFF + p * 128 + ((2 * qv) ^ srowswz(p))) =
                        __float2bfloat16(sc[t][r]);
                    if (!SPLIT && qv <= 48)
                        out_sc[(size_t)bm * (P_ * P_) + p * 49 + qv] = sc[t][r];
                }
            }
        }
    }
    __syncthreads();

    // ---- Phase 4: cov MFMA: cacc = Gb . Scb^T (K=64); T2 = rowmean in-reg ----
    f32x4 cacc[4] = {f32x4{0,0,0,0}, f32x4{0,0,0,0}, f32x4{0,0,0,0}, f32x4{0,0,0,0}};
    {
        const int arow = 16 * wid + l15;
        #pragma unroll
        for (int kc = 0; kc < 2; ++kc) {
            const int cb = 64 * kc + 16 * lh;
            const short8 af = *(const short8*)(smem + GB_OFF + arow * 128 + (cb ^ srowswz(arow)));
            #pragma unroll
            for (int t = 0; t < 4; ++t) {
                const int brow = 16 * t + l15;
                const short8 bf = *(const short8*)(smem + SCB_OFF + brow * 128 + (cb ^ srowswz(brow)));
                cacc[t] = __builtin_amdgcn_mfma_f32_16x16x32_bf16(af, bf, cacc[t], 0, 0, 0);
            }
        }
    }
    float t2[4];
    {
        #pragma unroll
        for (int r = 0; r < 4; ++r) {
            float s_ = cacc[0][r] + cacc[1][r] + cacc[2][r] + ((l15 == 0) ? cacc[3][r] : 0.f);
            #pragma unroll
            for (int d = 1; d < 16; d <<= 1) s_ += __shfl_xor(s_, d);
            t2[r] = s_ * (1.f / 49.f);
        }
    }
    __syncthreads();

    // ---- Phase 5: cv = (cacc - T2)/49; L = Sc + cv; Lb LDS write ----
    {
        #pragma unroll
        for (int t = 0; t < 4; ++t) {
            const int qv = 16 * t + l15;
            #pragma unroll
            for (int r = 0; r < 4; ++r) {
                const int p = 16 * wid + 4 * lh + r;
                if (p <= 48 && qv <= 48) {
                    const float cv = (cacc[t][r] - t2[r]) * (1.f / 49.f);
                    const float lv = sc[t][r] + cv;
                    if (!SPLIT) {
                        out_cov[(size_t)bm * (P_ * P_) + p * 49 + qv] = cv;
                        out_l  [(size_t)bm * (P_ * P_) + p * 49 + qv] = lv;
                    }
                    *(__hip_bfloat16*)(smem + GB_OFF + p * 128 + ((2 * qv) ^ srowswz(p))) =
                        __float2bfloat16(lv);
                }
            }
        }
    }
    __syncthreads();

    // ---- Phase 6: Ec^T = A^T . L^T (D[c][p]); wave wid -> c in [64wid, +64) ----
    {
        f32x4 acc[4][4];   // [ct][pt]
        #pragma unroll
        for (int i = 0; i < 4; ++i)
            #pragma unroll
            for (int j2 = 0; j2 < 4; ++j2) acc[i][j2] = f32x4{0, 0, 0, 0};

        #pragma unroll
        for (int kc = 0; kc < 2; ++kc) {
            const int cb = 64 * kc + 16 * lh;
            short8 bf[4];
            #pragma unroll
            for (int pt = 0; pt < 4; ++pt) {
                const int brow = 16 * pt + l15;
                bf[pt] = *(const short8*)(smem + GB_OFF + brow * 128 + (cb ^ srowswz(brow)));
            }
            #pragma unroll
            for (int ct = 0; ct < 4; ++ct) {
                const int c = 64 * wid + 16 * ct + l15;
                short8 af;
                #pragma unroll
                for (int j = 0; j < 8; ++j) {
                    const int q2 = 32 * kc + 8 * lh + j;
                    af[j] = *(const short*)(smem + SA_OFF + q2 * 512 + ((2 * c) ^ srowswz(q2)));
                }
                #pragma unroll
                for (int pt = 0; pt < 4; ++pt)
                    acc[ct][pt] = __builtin_amdgcn_mfma_f32_16x16x32_bf16(af, bf[pt], acc[ct][pt], 0, 0, 0);
            }
        }

        if (SPLIT) {
            // Wave-native packed ws stores: 32 x (64 lanes x 4B = 256B full lines).
            unsigned int* wec = ws_ec + ((size_t)bm * 4 + wid) * 2048;
            #pragma unroll
            for (int ct = 0; ct < 4; ++ct)
                #pragma unroll
                for (int pt = 0; pt < 4; ++pt)
                    #pragma unroll
                    for (int rp = 0; rp < 2; ++rp)
                        wec[(((ct * 4) + pt) * 2 + rp) * 64 + lane] =
                            packbf(acc[ct][pt][2 * rp], acc[ct][pt][2 * rp + 1]);
            // Deferred fp32 Sc/cov/L outputs (bf16-rounded; rel err ~0.4%).
            float* sc_g  = out_sc  + (size_t)bm * (P_ * P_);
            float* cov_g = out_cov + (size_t)bm * (P_ * P_);
            float* l_g   = out_l   + (size_t)bm * (P_ * P_);
            for (int e = tid; e < P_ * P_; e += 256) {
                const int p = e / 49, q = e - 49 * p;
                const float scv = bf2f_s(*(const short*)(smem + SCB_OFF + p * 128 + ((2 * q) ^ srowswz(p))));
                const float lvv = bf2f_s(*(const short*)(smem + GB_OFF  + p * 128 + ((2 * q) ^ srowswz(p))));
                sc_g[e]  = scv;
                l_g[e]   = lvv;
                cov_g[e] = lvv - scv;
            }
        } else {
            #pragma unroll
            for (int pt = 0; pt < 4; ++pt) {
                const int p = 16 * pt + l15;
                if (p > 48) continue;
                const int i = p / 7, j = p - 7 * (p / 7);
                const size_t base = xpatch + (size_t)i * W_ + j;
                #pragma unroll
                for (int ct = 0; ct < 4; ++ct) {
                    #pragma unroll
                    for (int r = 0; r < 4; ++r) {
                        const int c = 64 * wid + 16 * ct + 4 * lh + r;
                        const size_t g = base + (size_t)c * HW_;
                        const float ec = acc[ct][pt][r];
                        const float xv = bf2f_s(*(const short*)(smem + SA_OFF + p * 512 + ((2 * c) ^ srowswz(p))));
                        out_ec [g] = ec;
                        out_img[g] = xv * fmaf(beta, ec, xv);
                    }
                }
            }
        }
    }
}

// Fold: block = (b, c-quad, mh). Stage 32 patches' packed Ec uints for the
// 4 channels (64B-aligned full-line reads), unpack to lec[4][32][64], read x
// coalesced fp32, emit out_img/out_ec as full-line float4 stores.
__global__ __launch_bounds__(256)
void fold_kernel(const unsigned int* __restrict__ ws_ec,
                 const float* __restrict__ x, const float* __restrict__ betap,
                 float* __restrict__ out_img, float* __restrict__ out_ec)
{
    __shared__ short lec[4][32][64];   // 16,384 B

    const int bid = blockIdx.x;
    const int mh  = bid & 31;
    const int bcg = bid >> 5;          // b*64 + cgroup
    const int b   = bcg >> 6;
    const int c0  = (bcg & 63) << 2;
    const int t   = threadIdx.x;
    const float beta = betap[0];

    const int widc = c0 >> 6;
    const int ctc  = (c0 >> 4) & 3;
    const int lhc  = (c0 >> 2) & 3;

    // Stage: 32 patches x 128 uints (pt x rp x l15) = 4096 uint loads.
    for (int s = t; s < 4096; s += 256) {
        const int k   = s >> 7;          // patch (mw)
        const int rem = s & 127;
        const int pt  = rem >> 5;
        const int rp  = (rem >> 4) & 1;
        const int l15 = rem & 15;
        const size_t bm = (size_t)(b << 10) + (mh << 5) + k;
        const unsigned int v = ws_ec[(bm * 4 + widc) * 2048 +
                                     ((ctc * 4 + pt) * 2 + rp) * 64 + lhc * 16 + l15];
        const int p = pt * 16 + l15;
        lec[2 * rp]     [k][p] = (short)(v & 0xFFFF);
        lec[2 * rp + 1] [k][p] = (short)(v >> 16);
    }
    __syncthreads();

    // Emit: 4 channels x 7 rows x 56 float4s = 1568 iterations.
    for (int idx = t; idx < 1568; idx += 256) {
        const int cc = idx / 392;
        const int r2 = idx - cc * 392;
        const int i  = r2 / 56;
        const int w0 = (r2 - i * 56) * 4;
        const size_t g = (((size_t)(b * C_ + c0 + cc)) * H_ + (size_t)mh * 7 + i) * W_ + w0;
        const float4 xv = *(const float4*)&x[g];
        float4 vo, ve;
        #pragma unroll
        for (int e = 0; e < 4; ++e) {
            const int w  = w0 + e;
            const int mw = w / 7;
            const int p  = i * 7 + (w - mw * 7);
            const float ec = bf2f_s(lec[cc][mw][p]);
            const float xe = ((const float*)&xv)[e];
            ((float*)&ve)[e] = ec;
            ((float*)&vo)[e] = xe * fmaf(beta, ec, xe);
        }
        *(float4*)&out_ec [g] = ve;
        *(float4*)&out_img[g] = vo;
    }
}

extern "C" void kernel_launch(void* const* d_in, const int* in_sizes, int n_in,
                              void* d_out, int out_size, void* d_ws, size_t ws_size,
                              hipStream_t stream) {
    const float* x    = (const float*)d_in[0];
    const float* beta = (const float*)d_in[1];
    float* out = (float*)d_out;

    if (ws_size >= WS_NEED) {
        unsigned int* ws_ec = (unsigned int*)d_ws;
        psa_kernel<true><<<dim3(4 * M_), dim3(256), 0, stream>>>(
            x, beta, out, out + OFF_SC, out + OFF_COV, out + OFF_L, out + OFF_EC,
            ws_ec);
        fold_kernel<<<dim3(8192), dim3(256), 0, stream>>>(
            ws_ec, x, beta, out, out + OFF_EC);
    } else {
        psa_kernel<false><<<dim3(4 * M_), dim3(256), 0, stream>>>(
            x, beta, out, out + OFF_SC, out + OFF_COV, out + OFF_L, out + OFF_EC,
            nullptr);
    }
}

// Round 15
// 266.513 us; speedup vs baseline: 1.5982x; 1.0476x over previous
//
#include <hip/hip_runtime.h>
#include <hip/hip_bf16.h>
#include <cstdint>
#include <cstddef>

constexpr int C_  = 256;
constexpr int H_  = 224;
constexpr int W_  = 224;
constexpr int P_  = 49;
constexpr int M_  = 1024;
constexpr int HW_ = H_ * W_;

constexpr size_t IMG_ELEMS = (size_t)4 * C_ * H_ * W_;
constexpr size_t SCO_ELEMS = (size_t)4 * M_ * P_ * P_;
constexpr size_t OFF_SC  = IMG_ELEMS;
constexpr size_t OFF_COV = OFF_SC  + SCO_ELEMS;
constexpr size_t OFF_L   = OFF_COV + SCO_ELEMS;
constexpr size_t OFF_EC  = OFF_L   + SCO_ELEMS;

typedef __attribute__((ext_vector_type(8))) short short8;
typedef __attribute__((ext_vector_type(4))) float f32x4;

// Workspace: Ec wave-native packed, TRIMMED to valid tokens.
// Per (bm, wid): 1568 uints (6272B):
//   main [0,1536): idx = ((ct*3 + pt)*64 + lane)*2 + rp   (pt = 0..2, p<48)
//     uint = pack(bf16 Ec[c_lo], bf16 Ec[c_hi]), c = 64wid+16ct+4lh+2rp(+hi)
//   tail [1536,1568): p=48 row: idx = 1536 + lh*8 + ct*2 + rp (l15==0 lanes)
// psa stores: 12 x uint2 (512B/wave-instr) + 8 predicated tail stores.
constexpr size_t WSW_UINTS = 1568;                             // per wave
constexpr size_t WS_NEED   = (size_t)4096 * 4 * WSW_UINTS * 4; // 102,760,448 B

// K1 LDS map (47,488 B -> 3 blocks/CU):
constexpr int SA_OFF  = 0;        // 64 rows x 512B bf16 swizzled (49..63 = 0)
constexpr int GB_OFF  = 32768;    // 64 x 128B bf16 (G-u) -> Lb overlay (49..63 zeroed)
constexpr int SCB_OFF = 40960;    // 49 x 128B bf16 Sc
constexpr int U_OFF   = 47232;    // 64 f32
constexpr int SMEM_BYTES = 47488;

__device__ __forceinline__ int srowswz(int r) { return ((r ^ (r >> 3)) & 7) << 4; }

__device__ __forceinline__ short f2bf_s(float v) {
    __hip_bfloat16 b = __float2bfloat16(v);
    return *reinterpret_cast<short*>(&b);
}
__device__ __forceinline__ float bf2f_s(short s) {
    __hip_bfloat16 b = *reinterpret_cast<__hip_bfloat16*>(&s);
    return __bfloat162float(b);
}
__device__ __forceinline__ unsigned int packbf(float lo, float hi) {
    return (unsigned int)(unsigned short)f2bf_s(lo) |
           ((unsigned int)(unsigned short)f2bf_s(hi) << 16);
}

template<bool SPLIT>
__global__ __launch_bounds__(256, 3)
void psa_kernel(const float* __restrict__ x, const float* __restrict__ betap,
                float* __restrict__ out_img, float* __restrict__ out_sc,
                float* __restrict__ out_cov, float* __restrict__ out_l,
                float* __restrict__ out_ec,
                unsigned int* __restrict__ ws_ec)
{
    __shared__ __align__(16) unsigned char smem[SMEM_BYTES];
    float* uArr = (float*)(smem + U_OFF);

    const int tid = threadIdx.x;
    const int bid = blockIdx.x;
    const int bm  = ((bid & 7) << 9) | (bid >> 3);   // XCD-bijective swizzle
    const int b   = bm >> 10;
    const int m   = bm & (M_ - 1);
    const int mh  = m >> 5;
    const int mw  = m & 31;
    const float beta = betap[0];
    const size_t xpatch = (((size_t)b * C_ * H_) + (size_t)mh * 7) * W_ + (size_t)mw * 7;

    const int wid = tid >> 6, lane = tid & 63, l15 = lane & 15, lh = lane >> 4;

    // ---- Phase 0: stage x -> sA (lane = token, 8ch per ds_write_b128) ----
    {
        const int p = lane;
        const int i = p / 7, j = p - 7 * (p / 7);
        const float* xp = x + xpatch + (size_t)i * W_ + j + (size_t)(64 * wid) * HW_;
        const int swzp = srowswz(p);
        unsigned char* sbase = smem + SA_OFF + p * 512 + 128 * wid;
        #pragma unroll
        for (int g = 0; g < 8; ++g) {
            short8 pk;
            if (p < P_) {
                #pragma unroll
                for (int k = 0; k < 8; ++k)
                    pk[k] = f2bf_s(xp[(size_t)(8 * g + k) * HW_]);
            } else {
                pk = short8{0, 0, 0, 0, 0, 0, 0, 0};
            }
            *(short8*)(sbase + ((16 * g) ^ swzp)) = pk;
        }
    }
    __syncthreads();

    // ---- Phase 1: G = A A^T (MFMA, K=256); G stays in registers ----
    f32x4 gacc[4] = {f32x4{0,0,0,0}, f32x4{0,0,0,0}, f32x4{0,0,0,0}, f32x4{0,0,0,0}};
    {
        const int arow = 16 * wid + l15;
        #pragma unroll
        for (int kc = 0; kc < 8; ++kc) {
            const int cb = 64 * kc + 16 * lh;
            const short8 af = *(const short8*)(smem + SA_OFF + arow * 512 + (cb ^ srowswz(arow)));
            #pragma unroll
            for (int t = 0; t < 4; ++t) {
                const int brow = 16 * t + l15;
                const short8 bf = *(const short8*)(smem + SA_OFF + brow * 512 + (cb ^ srowswz(brow)));
                gacc[t] = __builtin_amdgcn_mfma_f32_16x16x32_bf16(af, bf, gacc[t], 0, 0, 0);
            }
        }
    }

    // ---- Phase 2: in-register row stats; u = rowmean (G symmetric) ----
    float mx[4];
    {
        #pragma unroll
        for (int r = 0; r < 4; ++r) {
            const int p = 16 * wid + 4 * lh + r;
            float m_ = fmaxf(fmaxf(gacc[0][r], gacc[1][r]), gacc[2][r]);
            m_ = fmaxf(m_, (l15 == 0) ? gacc[3][r] : -3.4e38f);
            float s_ = gacc[0][r] + gacc[1][r] + gacc[2][r] + ((l15 == 0) ? gacc[3][r] : 0.f);
            #pragma unroll
            for (int d = 1; d < 16; d <<= 1) {
                m_ = fmaxf(m_, __shfl_xor(m_, d));
                s_ += __shfl_xor(s_, d);
            }
            mx[r] = m_;
            if (l15 == 0 && p <= 48) uArr[p] = s_ * (1.f / 49.f);
        }
    }
    __syncthreads();

    // ---- Phase 3: Gb = bf16(G-u); in-reg exp/rowsum/scale; Scb.
    // Also zero Gb rows 49..63 (read by phase 6's B-fragments). ----
    float sc[4][4];
    {
        for (int s = tid; s < 120; s += 256)
            *(short8*)(smem + GB_OFF + 49 * 128 + s * 16) = short8{0,0,0,0,0,0,0,0};
        #pragma unroll
        for (int r = 0; r < 4; ++r) {
            const int p = 16 * wid + 4 * lh + r;
            if (p <= 48) {
                #pragma unroll
                for (int t = 0; t < 4; ++t) {
                    const int qv = 16 * t + l15;
                    const float gv = (qv <= 48) ? (gacc[t][r] - uArr[qv]) : 0.f;
                    *(__hip_bfloat16*)(smem + GB_OFF + p * 128 + ((2 * qv) ^ srowswz(p))) =
                        __float2bfloat16(gv);
                }
            }
            float e[4];
            #pragma unroll
            for (int t = 0; t < 4; ++t) {
                const int qv = 16 * t + l15;
                e[t] = (qv <= 48) ? __expf(gacc[t][r] - mx[r]) : 0.f;
            }
            float s_ = e[0] + e[1] + e[2] + e[3];
            #pragma unroll
            for (int d = 1; d < 16; d <<= 1) s_ += __shfl_xor(s_, d);
            const float rinv = 1.f / s_;
            #pragma unroll
            for (int t = 0; t < 4; ++t) sc[t][r] = e[t] * rinv;
            if (p <= 48) {
                #pragma unroll
                for (int t = 0; t < 4; ++t) {
                    const int qv = 16 * t + l15;
                    *(__hip_bfloat16*)(smem + SCB_OFF + p * 128 + ((2 * qv) ^ srowswz(p))) =
                        __float2bfloat16(sc[t][r]);
                    if (!SPLIT && qv <= 48)
                        out_sc[(size_t)bm * (P_ * P_) + p * 49 + qv] = sc[t][r];
                }
            }
        }
    }
    __syncthreads();

    // ---- Phase 4: cov MFMA: cacc = Gb . Scb^T (K=64); T2 = rowmean in-reg ----
    f32x4 cacc[4] = {f32x4{0,0,0,0}, f32x4{0,0,0,0}, f32x4{0,0,0,0}, f32x4{0,0,0,0}};
    {
        const int arow = 16 * wid + l15;
        #pragma unroll
        for (int kc = 0; kc < 2; ++kc) {
            const int cb = 64 * kc + 16 * lh;
            const short8 af = *(const short8*)(smem + GB_OFF + arow * 128 + (cb ^ srowswz(arow)));
            #pragma unroll
            for (int t = 0; t < 4; ++t) {
                const int brow = 16 * t + l15;
                const short8 bf = *(const short8*)(smem + SCB_OFF + brow * 128 + (cb ^ srowswz(brow)));
                cacc[t] = __builtin_amdgcn_mfma_f32_16x16x32_bf16(af, bf, cacc[t], 0, 0, 0);
            }
        }
    }
    float t2[4];
    {
        #pragma unroll
        for (int r = 0; r < 4; ++r) {
            float s_ = cacc[0][r] + cacc[1][r] + cacc[2][r] + ((l15 == 0) ? cacc[3][r] : 0.f);
            #pragma unroll
            for (int d = 1; d < 16; d <<= 1) s_ += __shfl_xor(s_, d);
            t2[r] = s_ * (1.f / 49.f);
        }
    }
    __syncthreads();

    // ---- Phase 5: cv = (cacc - T2)/49; L = Sc + cv; Lb LDS write ----
    {
        #pragma unroll
        for (int t = 0; t < 4; ++t) {
            const int qv = 16 * t + l15;
            #pragma unroll
            for (int r = 0; r < 4; ++r) {
                const int p = 16 * wid + 4 * lh + r;
                if (p <= 48 && qv <= 48) {
                    const float cv = (cacc[t][r] - t2[r]) * (1.f / 49.f);
                    const float lv = sc[t][r] + cv;
                    if (!SPLIT) {
                        out_cov[(size_t)bm * (P_ * P_) + p * 49 + qv] = cv;
                        out_l  [(size_t)bm * (P_ * P_) + p * 49 + qv] = lv;
                    }
                    *(__hip_bfloat16*)(smem + GB_OFF + p * 128 + ((2 * qv) ^ srowswz(p))) =
                        __float2bfloat16(lv);
                }
            }
        }
    }
    __syncthreads();

    // ---- Phase 6: Ec^T = A^T . L^T (D[c][p]); wave wid -> c in [64wid, +64) ----
    {
        f32x4 acc[4][4];   // [ct][pt]
        #pragma unroll
        for (int i = 0; i < 4; ++i)
            #pragma unroll
            for (int j2 = 0; j2 < 4; ++j2) acc[i][j2] = f32x4{0, 0, 0, 0};

        #pragma unroll
        for (int kc = 0; kc < 2; ++kc) {
            const int cb = 64 * kc + 16 * lh;
            short8 bf[4];
            #pragma unroll
            for (int pt = 0; pt < 4; ++pt) {
                const int brow = 16 * pt + l15;
                bf[pt] = *(const short8*)(smem + GB_OFF + brow * 128 + (cb ^ srowswz(brow)));
            }
            #pragma unroll
            for (int ct = 0; ct < 4; ++ct) {
                const int c = 64 * wid + 16 * ct + l15;
                short8 af;
                #pragma unroll
                for (int j = 0; j < 8; ++j) {
                    const int q2 = 32 * kc + 8 * lh + j;
                    af[j] = *(const short*)(smem + SA_OFF + q2 * 512 + ((2 * c) ^ srowswz(q2)));
                }
                #pragma unroll
                for (int pt = 0; pt < 4; ++pt)
                    acc[ct][pt] = __builtin_amdgcn_mfma_f32_16x16x32_bf16(af, bf[pt], acc[ct][pt], 0, 0, 0);
            }
        }

        if (SPLIT) {
            // Trimmed wave-native ws: 12 uint2 stores (512B/instr) + p=48 tail.
            unsigned int* wec = ws_ec + ((size_t)bm * 4 + wid) * WSW_UINTS;
            #pragma unroll
            for (int ct = 0; ct < 4; ++ct) {
                #pragma unroll
                for (int pt = 0; pt < 3; ++pt) {
                    uint2 v;
                    v.x = packbf(acc[ct][pt][0], acc[ct][pt][1]);
                    v.y = packbf(acc[ct][pt][2], acc[ct][pt][3]);
                    *(uint2*)&wec[((ct * 3 + pt) * 64 + lane) * 2] = v;
                }
            }
            if (l15 == 0) {   // p = 48 row (pt == 3, l15 == 0 only valid)
                #pragma unroll
                for (int ct = 0; ct < 4; ++ct)
                    #pragma unroll
                    for (int rp = 0; rp < 2; ++rp)
                        wec[1536 + lh * 8 + ct * 2 + rp] =
                            packbf(acc[ct][3][2 * rp], acc[ct][3][2 * rp + 1]);
            }
            // Deferred fp32 Sc/cov/L outputs (bf16-rounded; rel err ~0.4%).
            float* sc_g  = out_sc  + (size_t)bm * (P_ * P_);
            float* cov_g = out_cov + (size_t)bm * (P_ * P_);
            float* l_g   = out_l   + (size_t)bm * (P_ * P_);
            for (int e = tid; e < P_ * P_; e += 256) {
                const int p = e / 49, q = e - 49 * p;
                const float scv = bf2f_s(*(const short*)(smem + SCB_OFF + p * 128 + ((2 * q) ^ srowswz(p))));
                const float lvv = bf2f_s(*(const short*)(smem + GB_OFF  + p * 128 + ((2 * q) ^ srowswz(p))));
                sc_g[e]  = scv;
                l_g[e]   = lvv;
                cov_g[e] = lvv - scv;
            }
        } else {
            #pragma unroll
            for (int pt = 0; pt < 4; ++pt) {
                const int p = 16 * pt + l15;
                if (p > 48) continue;
                const int i = p / 7, j = p - 7 * (p / 7);
                const size_t base = xpatch + (size_t)i * W_ + j;
                #pragma unroll
                for (int ct = 0; ct < 4; ++ct) {
                    #pragma unroll
                    for (int r = 0; r < 4; ++r) {
                        const int c = 64 * wid + 16 * ct + 4 * lh + r;
                        const size_t g = base + (size_t)c * HW_;
                        const float ec = acc[ct][pt][r];
                        const float xv = bf2f_s(*(const short*)(smem + SA_OFF + p * 512 + ((2 * c) ^ srowswz(p))));
                        out_ec [g] = ec;
                        out_img[g] = xv * fmaf(beta, ec, xv);
                    }
                }
            }
        }
    }
}

// Fold: block = (b, c-quad, mh). The 4 staged channels share (widc,ctc,lhc)
// and differ only in (rp, half) -> each uint pair feeds all 4 channels.
__global__ __launch_bounds__(256)
void fold_kernel(const unsigned int* __restrict__ ws_ec,
                 const float* __restrict__ x, const float* __restrict__ betap,
                 float* __restrict__ out_img, float* __restrict__ out_ec)
{
    __shared__ short lec[4][32][64];   // [rc][patch][p]; 16,384 B

    const int bid = blockIdx.x;
    const int mh  = bid & 31;
    const int bcg = bid >> 5;          // b*64 + cgroup
    const int b   = bcg >> 6;
    const int c0  = (bcg & 63) << 2;
    const int t   = threadIdx.x;
    const float beta = betap[0];

    const int widc = c0 >> 6;
    const int ctc  = (c0 >> 4) & 3;
    const int lhc  = (c0 >> 2) & 3;

    // Stage main: k(32) x pt(3) x l15(16) x rp(2) = 3072 uint loads
    // (consecutive threads -> consecutive uints, 128B runs).
    for (int s = t; s < 3072; s += 256) {
        const int k   = s / 96;
        const int rem = s - k * 96;       // pt*32 + l15*2 + rp
        const int pt  = rem >> 5;
        const int l15 = (rem >> 1) & 15;
        const int rp  = rem & 1;
        const size_t bm = (size_t)(b << 10) + (mh << 5) + k;
        const unsigned int v = ws_ec[(bm * 4 + widc) * WSW_UINTS +
                                     ((ctc * 3 + pt) * 64 + lhc * 16 + l15) * 2 + rp];
        const int p = pt * 16 + l15;
        lec[2 * rp]    [k][p] = (short)(v & 0xFFFF);
        lec[2 * rp + 1][k][p] = (short)(v >> 16);
    }
    // Stage tail p=48: k(32) x rp(2) = 64 loads.
    for (int s = t; s < 64; s += 256) {
        const int k = s >> 1, rp = s & 1;
        const size_t bm = (size_t)(b << 10) + (mh << 5) + k;
        const unsigned int v = ws_ec[(bm * 4 + widc) * WSW_UINTS + 1536 +
                                     lhc * 8 + ctc * 2 + rp];
        lec[2 * rp]    [k][48] = (short)(v & 0xFFFF);
        lec[2 * rp + 1][k][48] = (short)(v >> 16);
    }
    __syncthreads();

    // Emit: 4 channels x 7 rows x 56 float4s = 1568 iterations (full lines).
    for (int idx = t; idx < 1568; idx += 256) {
        const int cc = idx / 392;
        const int r2 = idx - cc * 392;
        const int i  = r2 / 56;
        const int w0 = (r2 - i * 56) * 4;
        const size_t g = (((size_t)(b * C_ + c0 + cc)) * H_ + (size_t)mh * 7 + i) * W_ + w0;
        const float4 xv = *(const float4*)&x[g];
        float4 vo, ve;
        #pragma unroll
        for (int e = 0; e < 4; ++e) {
            const int w  = w0 + e;
            const int mw = w / 7;
            const int p  = i * 7 + (w - mw * 7);
            const float ec = bf2f_s(lec[cc][mw][p]);
            const float xe = ((const float*)&xv)[e];
            ((float*)&ve)[e] = ec;
            ((float*)&vo)[e] = xe * fmaf(beta, ec, xe);
        }
        *(float4*)&out_ec [g] = ve;
        *(float4*)&out_img[g] = vo;
    }
}

extern "C" void kernel_launch(void* const* d_in, const int* in_sizes, int n_in,
                              void* d_out, int out_size, void* d_ws, size_t ws_size,
                              hipStream_t stream) {
    const float* x    = (const float*)d_in[0];
    const float* beta = (const float*)d_in[1];
    float* out = (float*)d_out;

    if (ws_size >= WS_NEED) {
        unsigned int* ws_ec = (unsigned int*)d_ws;
        psa_kernel<true><<<dim3(4 * M_), dim3(256), 0, stream>>>(
            x, beta, out, out + OFF_SC, out + OFF_COV, out + OFF_L, out + OFF_EC,
            ws_ec);
        fold_kernel<<<dim3(8192), dim3(256), 0, stream>>>(
            ws_ec, x, beta, out, out + OFF_EC);
    } else {
        psa_kernel<false><<<dim3(4 * M_), dim3(256), 0, stream>>>(
            x, beta, out, out + OFF_SC, out + OFF_COV, out + OFF_L, out + OFF_EC,
            nullptr);
    }
}